// Round 5
// baseline (388.196 us; speedup 1.0000x reference)
//
#include <hip/hip_runtime.h>
#include <math.h>

#define NPTS 32768
#define NB 32
#define PP 1024
#define KK 20

using bf16x8 = __attribute__((ext_vector_type(8))) short;
using f32x4 = __attribute__((ext_vector_type(4))) float;

// ---------------- workspace layout ----------------
constexpr size_t OFF_X1 = 0;                                  // x1h[N,64]bf16 + x1l[N,64]bf16
constexpr size_t OFF_IDX = OFF_X1 + (size_t)NPTS * 64 * 4;    // [N,20] i32
constexpr size_t OFF_U = OFF_IDX + (size_t)NPTS * KK * 4;     // u2 [N,128] f32
constexpr size_t OFF_V = OFF_U + (size_t)NPTS * 128 * 4;      // v2 [N,128] f32
constexpr size_t OFF_X2 = OFF_V + (size_t)NPTS * 128 * 4;     // x2h + x2l bf16 [N,128] each
constexpr size_t OFF_H = OFF_X2 + (size_t)NPTS * 128 * 4;     // h [N,128] f32
constexpr size_t OFF_PART = OFF_H + (size_t)NPTS * 128 * 4;   // 32*8*128 f32
constexpr size_t OFF_SQN = OFF_PART + (size_t)32 * 8 * 128 * 4;  // [N] f32
// pk lifetimes:
//  knn1 pk (N*8*20 u32 = 21 MB) @ OFF_U — dead before precompute1 writes u1/v1.
//  knn2 pk (N*16*20 u32 = 42 MB) @ OFF_U — written after edge_conv1 consumed
//    u1/v1, dead before pre2_mfma writes u2/v2 (spans U+V+start of X2; X2 is
//    dead until gathermax2).

// ---------------- branch-free register top-K (med3 insert) ----------------
// l sorted ascending. Descending in-place clamp pass: l[j] = med3(key, l[j-1], l[j])
// == min(max(key, l[j-1]), l[j]) since l[j-1] <= l[j]. Backend matches clamp
// -> v_med3_u32 (1 instr/slot). Reads use old values (descending order), so
// in-place is exact. Set semantics identical to the compare-swap version.
__device__ __forceinline__ void topk_insert(unsigned (&l)[KK], unsigned key) {
#pragma unroll
  for (int j = KK - 1; j >= 1; --j) {
    unsigned lo = l[j - 1] > key ? l[j - 1] : key;  // max
    l[j] = lo < l[j] ? lo : l[j];                   // min
  }
  l[0] = key < l[0] ? key : l[0];
}

__device__ __forceinline__ unsigned pack_key(float dist, int q) {
  return (__float_as_uint(dist) & 0xFFFFFC00u) | (unsigned)q;
}

// hi/lo bf16 split: |x - (hi+lo)| <= 2^-16 |x|
__device__ __forceinline__ void split_bf16(float x, short& hi, short& lo) {
  unsigned u = __float_as_uint(x);
  hi = (short)(u >> 16);
  float fh = __uint_as_float(u & 0xFFFF0000u);
  float r = x - fh;
  lo = (short)(__float_as_uint(r) >> 16);
}

// ---------------- kNN1 (D=3) ----------------
template <int S>
__global__ __launch_bounds__(256) void knn_topk3(const float* __restrict__ x,
                                                 unsigned* __restrict__ pk) {
  constexpr int CH = PP / S;
  int bx = blockIdx.x;
  int s = bx % S;
  int tile = (bx / S) % (PP / 256);
  int b = bx / (S * (PP / 256));
  int i = tile * 256 + threadIdx.x;
  const float* xb = x + (size_t)b * PP * 3;

  unsigned l[KK];
#pragma unroll
  for (int j = 0; j < KK; ++j) l[j] = 0xFFFFFFFFu;

  float xi0 = xb[(size_t)i * 3 + 0];
  float xi1 = xb[(size_t)i * 3 + 1];
  float xi2 = xb[(size_t)i * 3 + 2];
  for (int c = 0; c < CH; ++c) {
    int q = s * CH + c;  // block-uniform
    const float* cp = xb + (size_t)q * 3;
    float d0 = xi0 - cp[0], d1 = xi1 - cp[1], d2 = xi2 - cp[2];
    float dist = fmaf(d0, d0, fmaf(d1, d1, d2 * d2));
    topk_insert(l, pack_key(dist, q));
  }
  size_t base = ((size_t)b * PP + i) * S + s;
#pragma unroll
  for (int j = 0; j < KK; ++j) pk[base * KK + j] = l[j];
}

template <int S>
__global__ __launch_bounds__(256) void knn_merge(const unsigned* __restrict__ pk,
                                                 int* __restrict__ idx_out) {
  int p = blockIdx.x * 256 + threadIdx.x;
  const unsigned* g = pk + (size_t)p * S * KK;
  unsigned l[KK];
#pragma unroll
  for (int j = 0; j < KK; ++j) l[j] = g[j];
  for (int s = 1; s < S; ++s) {
    const unsigned* gs = g + s * KK;
#pragma unroll
    for (int j = 0; j < KK; ++j) topk_insert(l, gs[j]);
  }
#pragma unroll
  for (int j = 0; j < KK; ++j) idx_out[(size_t)p * KK + j] = (int)(l[j] & 1023u);
}

// ---------------- EdgeConv1 precompute ----------------
__global__ __launch_bounds__(256) void precompute1(const float* __restrict__ pos,
                                                   const float* __restrict__ W1,
                                                   const float* __restrict__ b1,
                                                   float* __restrict__ u1,
                                                   float* __restrict__ v1) {
  int gid = blockIdx.x * 256 + threadIdx.x;  // over N*64
  int i = gid >> 6, c = gid & 63;
  float p0 = pos[(size_t)i * 3 + 0], p1 = pos[(size_t)i * 3 + 1], p2 = pos[(size_t)i * 3 + 2];
  float a0 = W1[0 * 64 + c], a1 = W1[1 * 64 + c], a2 = W1[2 * 64 + c];
  float g0 = W1[3 * 64 + c], g1 = W1[4 * 64 + c], g2 = W1[5 * 64 + c];
  float v = fmaf(p0, g0, fmaf(p1, g1, p2 * g2));
  float u = b1[c];
  u = fmaf(p0, a0 - g0, u);
  u = fmaf(p1, a1 - g1, u);
  u = fmaf(p2, a2 - g2, u);
  u1[gid] = u;
  v1[gid] = v;
}

// ---------------- EdgeConv1 via MFMA ----------------
__global__ __launch_bounds__(256) void edge_conv1_mfma(
    const float* __restrict__ u1, const float* __restrict__ v1,
    const int* __restrict__ idx, const float* __restrict__ W2,
    const float* __restrict__ scale, const float* __restrict__ bias,
    const float* __restrict__ b2,
    short* __restrict__ x1h, short* __restrict__ x1l,
    float* __restrict__ sqn) {
  __shared__ float Cs[160 * 68];
  __shared__ int jt[160];
  __shared__ float xs[512];
  int tid = threadIdx.x;
  int p0 = blockIdx.x * 8;
  int b = p0 >> 10;
  if (tid < 160) {
    int e = tid;
    int i = p0 + e / 20;
    jt[e] = (b << 10) + idx[(size_t)i * KK + e % 20];
  }
  int w = tid >> 6, l = tid & 63, quad = l >> 4, lm = l & 15;
  int kq = quad * 8;
  float4 s00 = *(const float4*)(scale + kq);
  float4 s01 = *(const float4*)(scale + kq + 4);
  float4 s10 = *(const float4*)(scale + 32 + kq);
  float4 s11 = *(const float4*)(scale + 32 + kq + 4);
  float4 c00 = *(const float4*)(bias + kq);
  float4 c01 = *(const float4*)(bias + kq + 4);
  float4 c10 = *(const float4*)(bias + 32 + kq);
  float4 c11 = *(const float4*)(bias + 32 + kq + 4);
  bf16x8 Bh[4][2], Bl[4][2];
#pragma unroll
  for (int nt = 0; nt < 4; ++nt) {
#pragma unroll
    for (int ks = 0; ks < 2; ++ks) {
#pragma unroll
      for (int jj = 0; jj < 8; ++jj) {
        float wv = W2[(size_t)(ks * 32 + kq + jj) * 64 + nt * 16 + lm];
        short hi, lo;
        split_bf16(wv, hi, lo);
        Bh[nt][ks][jj] = hi;
        Bl[nt][ks][jj] = lo;
      }
    }
  }
  __syncthreads();

  for (int s = w; s < 10; s += 4) {
    f32x4 acc[4];
#pragma unroll
    for (int nt = 0; nt < 4; ++nt) acc[nt] = (f32x4){0.f, 0.f, 0.f, 0.f};
    int e = s * 16 + lm;
    int p = e / 20;
    int jrow = jt[e];
    const float* urow = u1 + (size_t)(p0 + p) * 64;
    const float* vrow = v1 + (size_t)jrow * 64;
#pragma unroll
    for (int ks = 0; ks < 2; ++ks) {
      int koff = ks * 32 + kq;
      float4 va = *(const float4*)(vrow + koff);
      float4 vb = *(const float4*)(vrow + koff + 4);
      float4 ua = *(const float4*)(urow + koff);
      float4 ub = *(const float4*)(urow + koff + 4);
      float4 sA = ks ? s10 : s00, sB = ks ? s11 : s01;
      float4 cA = ks ? c10 : c00, cB = ks ? c11 : c01;
      float hv[8];
      hv[0] = fmaxf(fmaf(ua.x + va.x, sA.x, cA.x), 0.f);
      hv[1] = fmaxf(fmaf(ua.y + va.y, sA.y, cA.y), 0.f);
      hv[2] = fmaxf(fmaf(ua.z + va.z, sA.z, cA.z), 0.f);
      hv[3] = fmaxf(fmaf(ua.w + va.w, sA.w, cA.w), 0.f);
      hv[4] = fmaxf(fmaf(ub.x + vb.x, sB.x, cB.x), 0.f);
      hv[5] = fmaxf(fmaf(ub.y + vb.y, sB.y, cB.y), 0.f);
      hv[6] = fmaxf(fmaf(ub.z + vb.z, sB.z, cB.z), 0.f);
      hv[7] = fmaxf(fmaf(ub.w + vb.w, sB.w, cB.w), 0.f);
      bf16x8 Ah, Al;
#pragma unroll
      for (int jj = 0; jj < 8; ++jj) {
        short hi, lo;
        split_bf16(hv[jj], hi, lo);
        Ah[jj] = hi;
        Al[jj] = lo;
      }
#pragma unroll
      for (int nt = 0; nt < 4; ++nt) {
        acc[nt] = __builtin_amdgcn_mfma_f32_16x16x32_bf16(Ah, Bh[nt][ks], acc[nt], 0, 0, 0);
        acc[nt] = __builtin_amdgcn_mfma_f32_16x16x32_bf16(Al, Bh[nt][ks], acc[nt], 0, 0, 0);
        acc[nt] = __builtin_amdgcn_mfma_f32_16x16x32_bf16(Ah, Bl[nt][ks], acc[nt], 0, 0, 0);
      }
    }
#pragma unroll
    for (int nt = 0; nt < 4; ++nt) {
#pragma unroll
      for (int r = 0; r < 4; ++r) {
        Cs[(size_t)(s * 16 + quad * 4 + r) * 68 + nt * 16 + lm] = acc[nt][r];
      }
    }
  }
  __syncthreads();
  for (int o = tid; o < 512; o += 256) {
    int p = o >> 6, c = o & 63;
    float m = -__builtin_inff();
    for (int k = 0; k < KK; ++k) m = fmaxf(m, Cs[(size_t)(p * 20 + k) * 68 + c]);
    m += b2[c];
    size_t gi = (size_t)(p0 + p) * 64 + c;
    short hi, lo;
    split_bf16(m, hi, lo);
    x1h[gi] = hi;
    x1l[gi] = lo;
    xs[o] = m;
  }
  __syncthreads();
  if (tid < 8) {
    float ss = 0.f;
    for (int c = 0; c < 64; ++c) {
      float v = xs[tid * 64 + c];
      ss = fmaf(v, v, ss);
    }
    sqn[p0 + tid] = ss;
  }
}

// ---------------- kNN2 via MFMA (S=4 candidate split) ----------------
__global__ __launch_bounds__(256) void knn2_mfma(const short* __restrict__ x1h,
                                                 const short* __restrict__ x1l,
                                                 const float* __restrict__ sqn,
                                                 unsigned* __restrict__ pk) {
  __shared__ float sqs[1024];
  int bx = blockIdx.x;
  int s = bx & 3;
  int pb = bx >> 2;
  int p0 = pb * 64;
  int b = p0 >> 10;
  int tid = threadIdx.x;
  for (int t = tid; t < 1024; t += 256) sqs[t] = sqn[(size_t)b * PP + t];
  int w = tid >> 6, l = tid & 63, quad = l >> 4, lm = l & 15;
  size_t gi = (size_t)p0 + w * 16 + lm;
  bf16x8 Bh[2], Bl[2];
#pragma unroll
  for (int ks = 0; ks < 2; ++ks) {
    Bh[ks] = *(const bf16x8*)(x1h + gi * 64 + ks * 32 + quad * 8);
    Bl[ks] = *(const bf16x8*)(x1l + gi * 64 + ks * 32 + quad * 8);
  }
  float sqi = sqn[gi];
  __syncthreads();
  unsigned list[KK];
#pragma unroll
  for (int j = 0; j < KK; ++j) list[j] = 0xFFFFFFFFu;
  for (int m0 = s * 256; m0 < s * 256 + 256; m0 += 16) {
    size_t ga = (size_t)b * PP + m0 + lm;
    f32x4 acc = (f32x4){0.f, 0.f, 0.f, 0.f};
#pragma unroll
    for (int ks = 0; ks < 2; ++ks) {
      bf16x8 Ah = *(const bf16x8*)(x1h + ga * 64 + ks * 32 + quad * 8);
      bf16x8 Al = *(const bf16x8*)(x1l + ga * 64 + ks * 32 + quad * 8);
      acc = __builtin_amdgcn_mfma_f32_16x16x32_bf16(Ah, Bh[ks], acc, 0, 0, 0);
      acc = __builtin_amdgcn_mfma_f32_16x16x32_bf16(Al, Bh[ks], acc, 0, 0, 0);
      acc = __builtin_amdgcn_mfma_f32_16x16x32_bf16(Ah, Bl[ks], acc, 0, 0, 0);
    }
#pragma unroll
    for (int r = 0; r < 4; ++r) {
      int q = m0 + quad * 4 + r;
      float dist = fmaxf(0.f, fmaf(-2.f, acc[r], sqi + sqs[q]));
      topk_insert(list, pack_key(dist, q));
    }
  }
  unsigned sub = s * 4 + quad;
  unsigned* dst = pk + ((size_t)gi * 16 + sub) * KK;
#pragma unroll
  for (int j = 0; j < KK; ++j) dst[j] = list[j];
}

// ---------------- EdgeConv2 precompute via MFMA ----------------
__global__ __launch_bounds__(256) void pre2_mfma(const short* __restrict__ x1h,
                                                 const short* __restrict__ x1l,
                                                 const float* __restrict__ cW,
                                                 const float* __restrict__ cb,
                                                 float* __restrict__ u2,
                                                 float* __restrict__ v2) {
  constexpr int BS = 72;
  __shared__ short Bh[128 * BS];
  __shared__ short Bl[128 * BS];
  int tid = threadIdx.x;
  int nh = blockIdx.x & 1;
  int p0 = (blockIdx.x >> 1) * 64;
  for (int t = tid; t < 64 * 128; t += 256) {
    int k = t >> 7, n = t & 127;
    float wb_ = cW[(size_t)(64 + k) * 128 + n];
    float wv = nh ? wb_ : (cW[(size_t)k * 128 + n] - wb_);
    short hi, lo;
    split_bf16(wv, hi, lo);
    Bh[n * BS + k] = hi;
    Bl[n * BS + k] = lo;
  }
  __syncthreads();
  int w = tid >> 6, l = tid & 63, quad = l >> 4, lm = l & 15;
  int row = p0 + w * 16 + lm;
  f32x4 acc[8];
#pragma unroll
  for (int nt = 0; nt < 8; ++nt) acc[nt] = (f32x4){0.f, 0.f, 0.f, 0.f};
#pragma unroll
  for (int ks = 0; ks < 2; ++ks) {
    int kb = ks * 32 + quad * 8;
    bf16x8 Ah = *(const bf16x8*)(x1h + (size_t)row * 64 + kb);
    bf16x8 Al = *(const bf16x8*)(x1l + (size_t)row * 64 + kb);
#pragma unroll
    for (int nt = 0; nt < 8; ++nt) {
      bf16x8 Wh = *(const bf16x8*)(Bh + (nt * 16 + lm) * BS + kb);
      bf16x8 Wl = *(const bf16x8*)(Bl + (nt * 16 + lm) * BS + kb);
      acc[nt] = __builtin_amdgcn_mfma_f32_16x16x32_bf16(Ah, Wh, acc[nt], 0, 0, 0);
      acc[nt] = __builtin_amdgcn_mfma_f32_16x16x32_bf16(Al, Wh, acc[nt], 0, 0, 0);
      acc[nt] = __builtin_amdgcn_mfma_f32_16x16x32_bf16(Ah, Wl, acc[nt], 0, 0, 0);
    }
  }
  float* out = nh ? v2 : u2;
  int prow = p0 + w * 16 + quad * 4;
#pragma unroll
  for (int nt = 0; nt < 8; ++nt) {
    int col = nt * 16 + lm;
    float bias = nh ? 0.f : cb[col];
#pragma unroll
    for (int r = 0; r < 4; ++r)
      out[(size_t)(prow + r) * 128 + col] = acc[nt][r] + bias;
  }
}

__global__ __launch_bounds__(256) void gathermax2(const float* __restrict__ u2,
                                                  const float* __restrict__ v2,
                                                  const int* __restrict__ idx,
                                                  short* __restrict__ x2h,
                                                  short* __restrict__ x2l) {
  int gid = blockIdx.x * 256 + threadIdx.x;  // over N*128
  int i = gid >> 7, c = gid & 127;
  int b = i >> 10;
  const int* myidx = idx + (size_t)i * KK;
  float m = -__builtin_inff();
  for (int k = 0; k < KK; ++k) {
    int j = (b << 10) + myidx[k];
    m = fmaxf(m, v2[(size_t)j * 128 + c]);
  }
  float x = u2[gid] + m;
  short hi, lo;
  split_bf16(x, hi, lo);
  x2h[gid] = hi;
  x2l[gid] = lo;
}

// ---------------- final linear via MFMA ----------------
__global__ __launch_bounds__(256) void lin_mfma(const short* __restrict__ x1h,
                                                const short* __restrict__ x1l,
                                                const short* __restrict__ x2h,
                                                const short* __restrict__ x2l,
                                                const float* __restrict__ LW,
                                                const float* __restrict__ lb,
                                                float* __restrict__ h) {
  constexpr int BS = 200;
  __shared__ short Bh[64 * BS];
  __shared__ short Bl[64 * BS];
  int tid = threadIdx.x;
  int nh = blockIdx.x & 1;
  int p0 = (blockIdx.x >> 1) * 64;
  for (int t = tid; t < 192 * 64; t += 256) {
    int k = t >> 6, n = t & 63;
    float wv = LW[(size_t)k * 128 + nh * 64 + n];
    short hi, lo;
    split_bf16(wv, hi, lo);
    Bh[n * BS + k] = hi;
    Bl[n * BS + k] = lo;
  }
  __syncthreads();
  int w = tid >> 6, l = tid & 63, quad = l >> 4, lm = l & 15;
  int row = p0 + w * 16 + lm;
  f32x4 acc[4];
#pragma unroll
  for (int nt = 0; nt < 4; ++nt) acc[nt] = (f32x4){0.f, 0.f, 0.f, 0.f};
#pragma unroll
  for (int ks = 0; ks < 6; ++ks) {
    int kb = ks * 32 + quad * 8;
    bf16x8 Ah, Al;
    if (ks < 2) {
      Ah = *(const bf16x8*)(x1h + (size_t)row * 64 + kb);
      Al = *(const bf16x8*)(x1l + (size_t)row * 64 + kb);
    } else {
      Ah = *(const bf16x8*)(x2h + (size_t)row * 128 + (kb - 64));
      Al = *(const bf16x8*)(x2l + (size_t)row * 128 + (kb - 64));
    }
#pragma unroll
    for (int nt = 0; nt < 4; ++nt) {
      bf16x8 Wh = *(const bf16x8*)(Bh + (nt * 16 + lm) * BS + kb);
      bf16x8 Wl = *(const bf16x8*)(Bl + (nt * 16 + lm) * BS + kb);
      acc[nt] = __builtin_amdgcn_mfma_f32_16x16x32_bf16(Ah, Wh, acc[nt], 0, 0, 0);
      acc[nt] = __builtin_amdgcn_mfma_f32_16x16x32_bf16(Al, Wh, acc[nt], 0, 0, 0);
      acc[nt] = __builtin_amdgcn_mfma_f32_16x16x32_bf16(Ah, Wl, acc[nt], 0, 0, 0);
    }
  }
  int prow = p0 + w * 16 + quad * 4;
#pragma unroll
  for (int nt = 0; nt < 4; ++nt) {
    int col = nh * 64 + nt * 16 + lm;
    float bias = lb[col];
#pragma unroll
    for (int r = 0; r < 4; ++r)
      h[(size_t)(prow + r) * 128 + col] = acc[nt][r] + bias;
  }
}

// ---------------- segment max ----------------
__global__ __launch_bounds__(128) void segmax_a(const float* __restrict__ h,
                                                float* __restrict__ part) {
  int b = blockIdx.x >> 3, chunk = blockIdx.x & 7;
  int c = threadIdx.x;
  float m = -__builtin_inff();
  for (int p = 0; p < 128; ++p) {
    size_t i = (size_t)b * PP + chunk * 128 + p;
    m = fmaxf(m, h[i * 128 + c]);
  }
  part[(size_t)blockIdx.x * 128 + c] = m;
}

__global__ __launch_bounds__(128) void segmax_b(const float* __restrict__ part,
                                                float* __restrict__ out) {
  int b = blockIdx.x;
  int c = threadIdx.x;
  float m = -__builtin_inff();
  for (int k = 0; k < 8; ++k) m = fmaxf(m, part[((size_t)b * 8 + k) * 128 + c]);
  out[(size_t)b * 128 + c] = m;
}

// ---------------- launch ----------------
extern "C" void kernel_launch(void* const* d_in, const int* in_sizes, int n_in,
                              void* d_out, int out_size, void* d_ws, size_t ws_size,
                              hipStream_t stream) {
  const float* pos = (const float*)d_in[0];
  const float* W1 = (const float*)d_in[2];
  const float* b1 = (const float*)d_in[3];
  const float* bn_s = (const float*)d_in[4];
  const float* bn_b = (const float*)d_in[5];
  const float* W2 = (const float*)d_in[6];
  const float* b2 = (const float*)d_in[7];
  const float* cW = (const float*)d_in[8];
  const float* cb = (const float*)d_in[9];
  const float* LW = (const float*)d_in[10];
  const float* lb = (const float*)d_in[11];
  float* out = (float*)d_out;

  char* ws = (char*)d_ws;
  short* x1h = (short*)(ws + OFF_X1);
  short* x1l = (short*)(ws + OFF_X1 + (size_t)NPTS * 64 * 2);
  int* idx = (int*)(ws + OFF_IDX);
  float* u1 = (float*)(ws + OFF_U);
  float* v1 = (float*)(ws + OFF_V);
  float* u2 = (float*)(ws + OFF_U);
  float* v2 = (float*)(ws + OFF_V);
  short* x2h = (short*)(ws + OFF_X2);
  short* x2l = (short*)(ws + OFF_X2 + (size_t)NPTS * 128 * 2);
  float* hbuf = (float*)(ws + OFF_H);
  float* part = (float*)(ws + OFF_PART);
  float* sqn = (float*)(ws + OFF_SQN);
  unsigned* pk = (unsigned*)(ws + OFF_U);  // see lifetime notes above

  // 1. kNN on pos (8-way split)
  knn_topk3<8><<<NB * 4 * 8, 256, 0, stream>>>(pos, pk);
  knn_merge<8><<<NPTS / 256, 256, 0, stream>>>(pk, idx);
  // 2. u1/v1
  precompute1<<<NPTS * 64 / 256, 256, 0, stream>>>(pos, W1, b1, u1, v1);
  // 3. EdgeConv1 (MFMA) -> x1 bf16 hi/lo + sqn
  edge_conv1_mfma<<<NPTS / 8, 256, 0, stream>>>(u1, v1, idx, W2, bn_s, bn_b, b2,
                                                x1h, x1l, sqn);
  // 4. kNN on x1 (MFMA distances, 4-way cand split x 4 quad sublists)
  knn2_mfma<<<NPTS / 64 * 4, 256, 0, stream>>>(x1h, x1l, sqn, pk);
  knn_merge<16><<<NPTS / 256, 256, 0, stream>>>(pk, idx);
  // 5. u2/v2 (MFMA)
  pre2_mfma<<<NPTS / 64 * 2, 256, 0, stream>>>(x1h, x1l, cW, cb, u2, v2);
  // 6. gather + max -> x2 bf16 hi/lo
  gathermax2<<<NPTS * 128 / 256, 256, 0, stream>>>(u2, v2, idx, x2h, x2l);
  // 7. final linear (MFMA) -> h
  lin_mfma<<<NPTS / 64 * 2, 256, 0, stream>>>(x1h, x1l, x2h, x2l, LW, lb, hbuf);
  // 8. segment max -> out
  segmax_a<<<NB * 8, 128, 0, stream>>>(hbuf, part);
  segmax_b<<<NB, 128, 0, stream>>>(part, out);
}

// Round 6
// 350.437 us; speedup vs baseline: 1.1077x; 1.1077x over previous
//
#include <hip/hip_runtime.h>
#include <math.h>

#define NPTS 32768
#define NB 32
#define PP 1024
#define KK 20

using bf16x8 = __attribute__((ext_vector_type(8))) short;
using f32x4 = __attribute__((ext_vector_type(4))) float;

// ---------------- workspace layout ----------------
constexpr size_t OFF_X1 = 0;                                  // x1h[N,64]bf16 + x1l[N,64]bf16
constexpr size_t OFF_IDX = OFF_X1 + (size_t)NPTS * 64 * 4;    // [N,20] i32
constexpr size_t OFF_U = OFF_IDX + (size_t)NPTS * KK * 4;     // u2 [N,128] f32
constexpr size_t OFF_V = OFF_U + (size_t)NPTS * 128 * 4;      // v2 [N,128] f32
constexpr size_t OFF_X2 = OFF_V + (size_t)NPTS * 128 * 4;     // x2h + x2l bf16 [N,128] each
constexpr size_t OFF_H = OFF_X2 + (size_t)NPTS * 128 * 4;     // h [N,128] f32
constexpr size_t OFF_PART = OFF_H + (size_t)NPTS * 128 * 4;   // 32*8*128 f32
constexpr size_t OFF_SQN = OFF_PART + (size_t)32 * 8 * 128 * 4;  // [N] f32
// pk lifetimes (both at OFF_U):
//  knn1 pk (N*4*20 u32 = 10.5 MB) — dead before precompute1 writes u1/v1.
//  knn2 pk (N*8*20 u32 = 21 MB, spans U + start of V) — written after
//    edge_conv1 consumed u1/v1, dead before pre2_mfma writes u2/v2.

// ---------------- register top-K: v_med3_u32 insert ----------------
// l sorted ascending. l[j] = med3(key, l[j-1], l[j]) == min(max(key,l[j-1]),l[j])
// given l[j-1] <= l[j]. Descending in-place pass reads old values — exact.
// Inline asm because LLVM cannot prove the sortedness invariant to match med3.
__device__ __forceinline__ void topk_insert(unsigned (&l)[KK], unsigned key) {
#pragma unroll
  for (int j = KK - 1; j >= 1; --j) {
    unsigned r;
    asm("v_med3_u32 %0, %1, %2, %3" : "=v"(r) : "v"(key), "v"(l[j - 1]), "v"(l[j]));
    l[j] = r;
  }
  l[0] = key < l[0] ? key : l[0];
}

__device__ __forceinline__ unsigned pack_key(float dist, int q) {
  return (__float_as_uint(dist) & 0xFFFFFC00u) | (unsigned)q;
}

// hi/lo bf16 split: |x - (hi+lo)| <= 2^-16 |x|
__device__ __forceinline__ void split_bf16(float x, short& hi, short& lo) {
  unsigned u = __float_as_uint(x);
  hi = (short)(u >> 16);
  float fh = __uint_as_float(u & 0xFFFF0000u);
  float r = x - fh;
  lo = (short)(__float_as_uint(r) >> 16);
}

// ---------------- kNN1 (D=3) ----------------
template <int S>
__global__ __launch_bounds__(256) void knn_topk3(const float* __restrict__ x,
                                                 unsigned* __restrict__ pk) {
  constexpr int CH = PP / S;
  int bx = blockIdx.x;
  int s = bx % S;
  int tile = (bx / S) % (PP / 256);
  int b = bx / (S * (PP / 256));
  int i = tile * 256 + threadIdx.x;
  const float* xb = x + (size_t)b * PP * 3;

  unsigned l[KK];
#pragma unroll
  for (int j = 0; j < KK; ++j) l[j] = 0xFFFFFFFFu;

  float xi0 = xb[(size_t)i * 3 + 0];
  float xi1 = xb[(size_t)i * 3 + 1];
  float xi2 = xb[(size_t)i * 3 + 2];
  for (int c = 0; c < CH; ++c) {
    int q = s * CH + c;  // block-uniform
    const float* cp = xb + (size_t)q * 3;
    float d0 = xi0 - cp[0], d1 = xi1 - cp[1], d2 = xi2 - cp[2];
    float dist = fmaf(d0, d0, fmaf(d1, d1, d2 * d2));
    topk_insert(l, pack_key(dist, q));
  }
  size_t base = ((size_t)b * PP + i) * S + s;
#pragma unroll
  for (int j = 0; j < KK; ++j) pk[base * KK + j] = l[j];
}

template <int S>
__global__ __launch_bounds__(256) void knn_merge(const unsigned* __restrict__ pk,
                                                 int* __restrict__ idx_out) {
  int p = blockIdx.x * 256 + threadIdx.x;
  const unsigned* g = pk + (size_t)p * S * KK;
  unsigned l[KK];
#pragma unroll
  for (int j = 0; j < KK; ++j) l[j] = g[j];
  for (int s = 1; s < S; ++s) {
    const unsigned* gs = g + s * KK;
#pragma unroll
    for (int j = 0; j < KK; ++j) topk_insert(l, gs[j]);
  }
#pragma unroll
  for (int j = 0; j < KK; ++j) idx_out[(size_t)p * KK + j] = (int)(l[j] & 1023u);
}

// ---------------- EdgeConv1 precompute ----------------
__global__ __launch_bounds__(256) void precompute1(const float* __restrict__ pos,
                                                   const float* __restrict__ W1,
                                                   const float* __restrict__ b1,
                                                   float* __restrict__ u1,
                                                   float* __restrict__ v1) {
  int gid = blockIdx.x * 256 + threadIdx.x;  // over N*64
  int i = gid >> 6, c = gid & 63;
  float p0 = pos[(size_t)i * 3 + 0], p1 = pos[(size_t)i * 3 + 1], p2 = pos[(size_t)i * 3 + 2];
  float a0 = W1[0 * 64 + c], a1 = W1[1 * 64 + c], a2 = W1[2 * 64 + c];
  float g0 = W1[3 * 64 + c], g1 = W1[4 * 64 + c], g2 = W1[5 * 64 + c];
  float v = fmaf(p0, g0, fmaf(p1, g1, p2 * g2));
  float u = b1[c];
  u = fmaf(p0, a0 - g0, u);
  u = fmaf(p1, a1 - g1, u);
  u = fmaf(p2, a2 - g2, u);
  u1[gid] = u;
  v1[gid] = v;
}

// ---------------- EdgeConv1 via MFMA ----------------
__global__ __launch_bounds__(256) void edge_conv1_mfma(
    const float* __restrict__ u1, const float* __restrict__ v1,
    const int* __restrict__ idx, const float* __restrict__ W2,
    const float* __restrict__ scale, const float* __restrict__ bias,
    const float* __restrict__ b2,
    short* __restrict__ x1h, short* __restrict__ x1l,
    float* __restrict__ sqn) {
  __shared__ float Cs[160 * 68];
  __shared__ int jt[160];
  __shared__ float xs[512];
  int tid = threadIdx.x;
  int p0 = blockIdx.x * 8;
  int b = p0 >> 10;
  if (tid < 160) {
    int e = tid;
    int i = p0 + e / 20;
    jt[e] = (b << 10) + idx[(size_t)i * KK + e % 20];
  }
  int w = tid >> 6, l = tid & 63, quad = l >> 4, lm = l & 15;
  int kq = quad * 8;
  float4 s00 = *(const float4*)(scale + kq);
  float4 s01 = *(const float4*)(scale + kq + 4);
  float4 s10 = *(const float4*)(scale + 32 + kq);
  float4 s11 = *(const float4*)(scale + 32 + kq + 4);
  float4 c00 = *(const float4*)(bias + kq);
  float4 c01 = *(const float4*)(bias + kq + 4);
  float4 c10 = *(const float4*)(bias + 32 + kq);
  float4 c11 = *(const float4*)(bias + 32 + kq + 4);
  bf16x8 Bh[4][2], Bl[4][2];
#pragma unroll
  for (int nt = 0; nt < 4; ++nt) {
#pragma unroll
    for (int ks = 0; ks < 2; ++ks) {
#pragma unroll
      for (int jj = 0; jj < 8; ++jj) {
        float wv = W2[(size_t)(ks * 32 + kq + jj) * 64 + nt * 16 + lm];
        short hi, lo;
        split_bf16(wv, hi, lo);
        Bh[nt][ks][jj] = hi;
        Bl[nt][ks][jj] = lo;
      }
    }
  }
  __syncthreads();

  for (int s = w; s < 10; s += 4) {
    f32x4 acc[4];
#pragma unroll
    for (int nt = 0; nt < 4; ++nt) acc[nt] = (f32x4){0.f, 0.f, 0.f, 0.f};
    int e = s * 16 + lm;
    int p = e / 20;
    int jrow = jt[e];
    const float* urow = u1 + (size_t)(p0 + p) * 64;
    const float* vrow = v1 + (size_t)jrow * 64;
#pragma unroll
    for (int ks = 0; ks < 2; ++ks) {
      int koff = ks * 32 + kq;
      float4 va = *(const float4*)(vrow + koff);
      float4 vb = *(const float4*)(vrow + koff + 4);
      float4 ua = *(const float4*)(urow + koff);
      float4 ub = *(const float4*)(urow + koff + 4);
      float4 sA = ks ? s10 : s00, sB = ks ? s11 : s01;
      float4 cA = ks ? c10 : c00, cB = ks ? c11 : c01;
      float hv[8];
      hv[0] = fmaxf(fmaf(ua.x + va.x, sA.x, cA.x), 0.f);
      hv[1] = fmaxf(fmaf(ua.y + va.y, sA.y, cA.y), 0.f);
      hv[2] = fmaxf(fmaf(ua.z + va.z, sA.z, cA.z), 0.f);
      hv[3] = fmaxf(fmaf(ua.w + va.w, sA.w, cA.w), 0.f);
      hv[4] = fmaxf(fmaf(ub.x + vb.x, sB.x, cB.x), 0.f);
      hv[5] = fmaxf(fmaf(ub.y + vb.y, sB.y, cB.y), 0.f);
      hv[6] = fmaxf(fmaf(ub.z + vb.z, sB.z, cB.z), 0.f);
      hv[7] = fmaxf(fmaf(ub.w + vb.w, sB.w, cB.w), 0.f);
      bf16x8 Ah, Al;
#pragma unroll
      for (int jj = 0; jj < 8; ++jj) {
        short hi, lo;
        split_bf16(hv[jj], hi, lo);
        Ah[jj] = hi;
        Al[jj] = lo;
      }
#pragma unroll
      for (int nt = 0; nt < 4; ++nt) {
        acc[nt] = __builtin_amdgcn_mfma_f32_16x16x32_bf16(Ah, Bh[nt][ks], acc[nt], 0, 0, 0);
        acc[nt] = __builtin_amdgcn_mfma_f32_16x16x32_bf16(Al, Bh[nt][ks], acc[nt], 0, 0, 0);
        acc[nt] = __builtin_amdgcn_mfma_f32_16x16x32_bf16(Ah, Bl[nt][ks], acc[nt], 0, 0, 0);
      }
    }
#pragma unroll
    for (int nt = 0; nt < 4; ++nt) {
#pragma unroll
      for (int r = 0; r < 4; ++r) {
        Cs[(size_t)(s * 16 + quad * 4 + r) * 68 + nt * 16 + lm] = acc[nt][r];
      }
    }
  }
  __syncthreads();
  for (int o = tid; o < 512; o += 256) {
    int p = o >> 6, c = o & 63;
    float m = -__builtin_inff();
    for (int k = 0; k < KK; ++k) m = fmaxf(m, Cs[(size_t)(p * 20 + k) * 68 + c]);
    m += b2[c];
    size_t gi = (size_t)(p0 + p) * 64 + c;
    short hi, lo;
    split_bf16(m, hi, lo);
    x1h[gi] = hi;
    x1l[gi] = lo;
    xs[o] = m;
  }
  __syncthreads();
  if (tid < 8) {
    float ss = 0.f;
    for (int c = 0; c < 64; ++c) {
      float v = xs[tid * 64 + c];
      ss = fmaf(v, v, ss);
    }
    sqn[p0 + tid] = ss;
  }
}

// ---------------- kNN2 via MFMA (S=2 candidate split) ----------------
__global__ __launch_bounds__(256) void knn2_mfma(const short* __restrict__ x1h,
                                                 const short* __restrict__ x1l,
                                                 const float* __restrict__ sqn,
                                                 unsigned* __restrict__ pk) {
  __shared__ float sqs[1024];
  int bx = blockIdx.x;
  int s = bx & 1;
  int pb = bx >> 1;
  int p0 = pb * 64;
  int b = p0 >> 10;
  int tid = threadIdx.x;
  for (int t = tid; t < 1024; t += 256) sqs[t] = sqn[(size_t)b * PP + t];
  int w = tid >> 6, l = tid & 63, quad = l >> 4, lm = l & 15;
  size_t gi = (size_t)p0 + w * 16 + lm;
  bf16x8 Bh[2], Bl[2];
#pragma unroll
  for (int ks = 0; ks < 2; ++ks) {
    Bh[ks] = *(const bf16x8*)(x1h + gi * 64 + ks * 32 + quad * 8);
    Bl[ks] = *(const bf16x8*)(x1l + gi * 64 + ks * 32 + quad * 8);
  }
  float sqi = sqn[gi];
  __syncthreads();
  unsigned list[KK];
#pragma unroll
  for (int j = 0; j < KK; ++j) list[j] = 0xFFFFFFFFu;
  for (int m0 = s * 512; m0 < s * 512 + 512; m0 += 16) {
    size_t ga = (size_t)b * PP + m0 + lm;
    f32x4 acc = (f32x4){0.f, 0.f, 0.f, 0.f};
#pragma unroll
    for (int ks = 0; ks < 2; ++ks) {
      bf16x8 Ah = *(const bf16x8*)(x1h + ga * 64 + ks * 32 + quad * 8);
      bf16x8 Al = *(const bf16x8*)(x1l + ga * 64 + ks * 32 + quad * 8);
      acc = __builtin_amdgcn_mfma_f32_16x16x32_bf16(Ah, Bh[ks], acc, 0, 0, 0);
      acc = __builtin_amdgcn_mfma_f32_16x16x32_bf16(Al, Bh[ks], acc, 0, 0, 0);
      acc = __builtin_amdgcn_mfma_f32_16x16x32_bf16(Ah, Bl[ks], acc, 0, 0, 0);
    }
#pragma unroll
    for (int r = 0; r < 4; ++r) {
      int q = m0 + quad * 4 + r;
      float dist = fmaxf(0.f, fmaf(-2.f, acc[r], sqi + sqs[q]));
      topk_insert(list, pack_key(dist, q));
    }
  }
  unsigned sub = s * 4 + quad;
  unsigned* dst = pk + ((size_t)gi * 8 + sub) * KK;
#pragma unroll
  for (int j = 0; j < KK; ++j) dst[j] = list[j];
}

// ---------------- EdgeConv2 precompute via MFMA ----------------
__global__ __launch_bounds__(256) void pre2_mfma(const short* __restrict__ x1h,
                                                 const short* __restrict__ x1l,
                                                 const float* __restrict__ cW,
                                                 const float* __restrict__ cb,
                                                 float* __restrict__ u2,
                                                 float* __restrict__ v2) {
  constexpr int BS = 72;
  __shared__ short Bh[128 * BS];
  __shared__ short Bl[128 * BS];
  int tid = threadIdx.x;
  int nh = blockIdx.x & 1;
  int p0 = (blockIdx.x >> 1) * 64;
  for (int t = tid; t < 64 * 128; t += 256) {
    int k = t >> 7, n = t & 127;
    float wb_ = cW[(size_t)(64 + k) * 128 + n];
    float wv = nh ? wb_ : (cW[(size_t)k * 128 + n] - wb_);
    short hi, lo;
    split_bf16(wv, hi, lo);
    Bh[n * BS + k] = hi;
    Bl[n * BS + k] = lo;
  }
  __syncthreads();
  int w = tid >> 6, l = tid & 63, quad = l >> 4, lm = l & 15;
  int row = p0 + w * 16 + lm;
  f32x4 acc[8];
#pragma unroll
  for (int nt = 0; nt < 8; ++nt) acc[nt] = (f32x4){0.f, 0.f, 0.f, 0.f};
#pragma unroll
  for (int ks = 0; ks < 2; ++ks) {
    int kb = ks * 32 + quad * 8;
    bf16x8 Ah = *(const bf16x8*)(x1h + (size_t)row * 64 + kb);
    bf16x8 Al = *(const bf16x8*)(x1l + (size_t)row * 64 + kb);
#pragma unroll
    for (int nt = 0; nt < 8; ++nt) {
      bf16x8 Wh = *(const bf16x8*)(Bh + (nt * 16 + lm) * BS + kb);
      bf16x8 Wl = *(const bf16x8*)(Bl + (nt * 16 + lm) * BS + kb);
      acc[nt] = __builtin_amdgcn_mfma_f32_16x16x32_bf16(Ah, Wh, acc[nt], 0, 0, 0);
      acc[nt] = __builtin_amdgcn_mfma_f32_16x16x32_bf16(Al, Wh, acc[nt], 0, 0, 0);
      acc[nt] = __builtin_amdgcn_mfma_f32_16x16x32_bf16(Ah, Wl, acc[nt], 0, 0, 0);
    }
  }
  float* out = nh ? v2 : u2;
  int prow = p0 + w * 16 + quad * 4;
#pragma unroll
  for (int nt = 0; nt < 8; ++nt) {
    int col = nt * 16 + lm;
    float bias = nh ? 0.f : cb[col];
#pragma unroll
    for (int r = 0; r < 4; ++r)
      out[(size_t)(prow + r) * 128 + col] = acc[nt][r] + bias;
  }
}

__global__ __launch_bounds__(256) void gathermax2(const float* __restrict__ u2,
                                                  const float* __restrict__ v2,
                                                  const int* __restrict__ idx,
                                                  short* __restrict__ x2h,
                                                  short* __restrict__ x2l) {
  int gid = blockIdx.x * 256 + threadIdx.x;  // over N*128
  int i = gid >> 7, c = gid & 127;
  int b = i >> 10;
  const int* myidx = idx + (size_t)i * KK;
  float m = -__builtin_inff();
  for (int k = 0; k < KK; ++k) {
    int j = (b << 10) + myidx[k];
    m = fmaxf(m, v2[(size_t)j * 128 + c]);
  }
  float x = u2[gid] + m;
  short hi, lo;
  split_bf16(x, hi, lo);
  x2h[gid] = hi;
  x2l[gid] = lo;
}

// ---------------- final linear via MFMA ----------------
__global__ __launch_bounds__(256) void lin_mfma(const short* __restrict__ x1h,
                                                const short* __restrict__ x1l,
                                                const short* __restrict__ x2h,
                                                const short* __restrict__ x2l,
                                                const float* __restrict__ LW,
                                                const float* __restrict__ lb,
                                                float* __restrict__ h) {
  constexpr int BS = 200;
  __shared__ short Bh[64 * BS];
  __shared__ short Bl[64 * BS];
  int tid = threadIdx.x;
  int nh = blockIdx.x & 1;
  int p0 = (blockIdx.x >> 1) * 64;
  for (int t = tid; t < 192 * 64; t += 256) {
    int k = t >> 6, n = t & 63;
    float wv = LW[(size_t)k * 128 + nh * 64 + n];
    short hi, lo;
    split_bf16(wv, hi, lo);
    Bh[n * BS + k] = hi;
    Bl[n * BS + k] = lo;
  }
  __syncthreads();
  int w = tid >> 6, l = tid & 63, quad = l >> 4, lm = l & 15;
  int row = p0 + w * 16 + lm;
  f32x4 acc[4];
#pragma unroll
  for (int nt = 0; nt < 4; ++nt) acc[nt] = (f32x4){0.f, 0.f, 0.f, 0.f};
#pragma unroll
  for (int ks = 0; ks < 6; ++ks) {
    int kb = ks * 32 + quad * 8;
    bf16x8 Ah, Al;
    if (ks < 2) {
      Ah = *(const bf16x8*)(x1h + (size_t)row * 64 + kb);
      Al = *(const bf16x8*)(x1l + (size_t)row * 64 + kb);
    } else {
      Ah = *(const bf16x8*)(x2h + (size_t)row * 128 + (kb - 64));
      Al = *(const bf16x8*)(x2l + (size_t)row * 128 + (kb - 64));
    }
#pragma unroll
    for (int nt = 0; nt < 4; ++nt) {
      bf16x8 Wh = *(const bf16x8*)(Bh + (nt * 16 + lm) * BS + kb);
      bf16x8 Wl = *(const bf16x8*)(Bl + (nt * 16 + lm) * BS + kb);
      acc[nt] = __builtin_amdgcn_mfma_f32_16x16x32_bf16(Ah, Wh, acc[nt], 0, 0, 0);
      acc[nt] = __builtin_amdgcn_mfma_f32_16x16x32_bf16(Al, Wh, acc[nt], 0, 0, 0);
      acc[nt] = __builtin_amdgcn_mfma_f32_16x16x32_bf16(Ah, Wl, acc[nt], 0, 0, 0);
    }
  }
  int prow = p0 + w * 16 + quad * 4;
#pragma unroll
  for (int nt = 0; nt < 4; ++nt) {
    int col = nh * 64 + nt * 16 + lm;
    float bias = lb[col];
#pragma unroll
    for (int r = 0; r < 4; ++r)
      h[(size_t)(prow + r) * 128 + col] = acc[nt][r] + bias;
  }
}

// ---------------- segment max ----------------
__global__ __launch_bounds__(128) void segmax_a(const float* __restrict__ h,
                                                float* __restrict__ part) {
  int b = blockIdx.x >> 3, chunk = blockIdx.x & 7;
  int c = threadIdx.x;
  float m = -__builtin_inff();
  for (int p = 0; p < 128; ++p) {
    size_t i = (size_t)b * PP + chunk * 128 + p;
    m = fmaxf(m, h[i * 128 + c]);
  }
  part[(size_t)blockIdx.x * 128 + c] = m;
}

__global__ __launch_bounds__(128) void segmax_b(const float* __restrict__ part,
                                                float* __restrict__ out) {
  int b = blockIdx.x;
  int c = threadIdx.x;
  float m = -__builtin_inff();
  for (int k = 0; k < 8; ++k) m = fmaxf(m, part[((size_t)b * 8 + k) * 128 + c]);
  out[(size_t)b * 128 + c] = m;
}

// ---------------- launch ----------------
extern "C" void kernel_launch(void* const* d_in, const int* in_sizes, int n_in,
                              void* d_out, int out_size, void* d_ws, size_t ws_size,
                              hipStream_t stream) {
  const float* pos = (const float*)d_in[0];
  const float* W1 = (const float*)d_in[2];
  const float* b1 = (const float*)d_in[3];
  const float* bn_s = (const float*)d_in[4];
  const float* bn_b = (const float*)d_in[5];
  const float* W2 = (const float*)d_in[6];
  const float* b2 = (const float*)d_in[7];
  const float* cW = (const float*)d_in[8];
  const float* cb = (const float*)d_in[9];
  const float* LW = (const float*)d_in[10];
  const float* lb = (const float*)d_in[11];
  float* out = (float*)d_out;

  char* ws = (char*)d_ws;
  short* x1h = (short*)(ws + OFF_X1);
  short* x1l = (short*)(ws + OFF_X1 + (size_t)NPTS * 64 * 2);
  int* idx = (int*)(ws + OFF_IDX);
  float* u1 = (float*)(ws + OFF_U);
  float* v1 = (float*)(ws + OFF_V);
  float* u2 = (float*)(ws + OFF_U);
  float* v2 = (float*)(ws + OFF_V);
  short* x2h = (short*)(ws + OFF_X2);
  short* x2l = (short*)(ws + OFF_X2 + (size_t)NPTS * 128 * 2);
  float* hbuf = (float*)(ws + OFF_H);
  float* part = (float*)(ws + OFF_PART);
  float* sqn = (float*)(ws + OFF_SQN);
  unsigned* pk = (unsigned*)(ws + OFF_U);  // see lifetime notes above

  // 1. kNN on pos (4-way split)
  knn_topk3<4><<<NB * 4 * 4, 256, 0, stream>>>(pos, pk);
  knn_merge<4><<<NPTS / 256, 256, 0, stream>>>(pk, idx);
  // 2. u1/v1
  precompute1<<<NPTS * 64 / 256, 256, 0, stream>>>(pos, W1, b1, u1, v1);
  // 3. EdgeConv1 (MFMA) -> x1 bf16 hi/lo + sqn
  edge_conv1_mfma<<<NPTS / 8, 256, 0, stream>>>(u1, v1, idx, W2, bn_s, bn_b, b2,
                                                x1h, x1l, sqn);
  // 4. kNN on x1 (MFMA distances, 2-way cand split x 4 quad sublists)
  knn2_mfma<<<NPTS / 64 * 2, 256, 0, stream>>>(x1h, x1l, sqn, pk);
  knn_merge<8><<<NPTS / 256, 256, 0, stream>>>(pk, idx);
  // 5. u2/v2 (MFMA)
  pre2_mfma<<<NPTS / 64 * 2, 256, 0, stream>>>(x1h, x1l, cW, cb, u2, v2);
  // 6. gather + max -> x2 bf16 hi/lo
  gathermax2<<<NPTS * 128 / 256, 256, 0, stream>>>(u2, v2, idx, x2h, x2l);
  // 7. final linear (MFMA) -> h
  lin_mfma<<<NPTS / 64 * 2, 256, 0, stream>>>(x1h, x1l, x2h, x2l, LW, lb, hbuf);
  // 8. segment max -> out
  segmax_a<<<NB * 8, 128, 0, stream>>>(hbuf, part);
  segmax_b<<<NB, 128, 0, stream>>>(part, out);
}

// Round 7
// 340.791 us; speedup vs baseline: 1.1391x; 1.0283x over previous
//
#include <hip/hip_runtime.h>
#include <math.h>

#define NPTS 32768
#define NB 32
#define PP 1024
#define KK 20

using bf16x8 = __attribute__((ext_vector_type(8))) short;
using f32x4 = __attribute__((ext_vector_type(4))) float;

// ---------------- workspace layout ----------------
constexpr size_t OFF_X1 = 0;                                  // x1h[N,64]bf16 + x1l[N,64]bf16
constexpr size_t OFF_IDX = OFF_X1 + (size_t)NPTS * 64 * 4;    // [N,20] i32
constexpr size_t OFF_U = OFF_IDX + (size_t)NPTS * KK * 4;     // u2 [N,128] f32
constexpr size_t OFF_V = OFF_U + (size_t)NPTS * 128 * 4;      // v2 [N,128] f32
constexpr size_t OFF_X2 = OFF_V + (size_t)NPTS * 128 * 4;     // x2h + x2l bf16 [N,128] each
constexpr size_t OFF_H = OFF_X2 + (size_t)NPTS * 128 * 4;     // h [N,128] f32
constexpr size_t OFF_PART = OFF_H + (size_t)NPTS * 128 * 4;   // 32*8*128 f32
constexpr size_t OFF_SQN = OFF_PART + (size_t)32 * 8 * 128 * 4;  // [N] f32
// pk lifetimes (both at OFF_U):
//  knn1 pk (N*4*20 u32 = 10.5 MB) — dead before precompute1 writes u1/v1.
//  knn2 pk (N*8*20 u32 = 21 MB, spans U + start of V) — written after
//    edge_conv1 consumed u1/v1, dead before pre2_mfma writes u2/v2.

// ---------------- register top-K: v_med3_u32 insert ----------------
__device__ __forceinline__ void topk_insert(unsigned (&l)[KK], unsigned key) {
#pragma unroll
  for (int j = KK - 1; j >= 1; --j) {
    unsigned r;
    asm("v_med3_u32 %0, %1, %2, %3" : "=v"(r) : "v"(key), "v"(l[j - 1]), "v"(l[j]));
    l[j] = r;
  }
  l[0] = key < l[0] ? key : l[0];
}

__device__ __forceinline__ unsigned pack_key(float dist, int q) {
  return (__float_as_uint(dist) & 0xFFFFFC00u) | (unsigned)q;
}

// hi/lo bf16 split: |x - (hi+lo)| <= 2^-16 |x|
__device__ __forceinline__ void split_bf16(float x, short& hi, short& lo) {
  unsigned u = __float_as_uint(x);
  hi = (short)(u >> 16);
  float fh = __uint_as_float(u & 0xFFFF0000u);
  float r = x - fh;
  lo = (short)(__float_as_uint(r) >> 16);
}

// ---------------- kNN1 (D=3): LDS SoA + register prefetch ----------------
template <int S>
__global__ __launch_bounds__(256) void knn_topk3(const float* __restrict__ x,
                                                 unsigned* __restrict__ pk) {
  constexpr int CH = PP / S;
  __shared__ __align__(16) float xs[1024];
  __shared__ __align__(16) float ys[1024];
  __shared__ __align__(16) float zs[1024];
  int bx = blockIdx.x;
  int s = bx % S;
  int tile = (bx / S) % (PP / 256);
  int b = bx / (S * (PP / 256));
  int tid = threadIdx.x;
  const float* xb = x + (size_t)b * PP * 3;

  // stage cloud coords as SoA (values identical to global — bit-exact math)
  for (int t = tid; t < 768; t += 256) {
    float4 v = ((const float4*)xb)[t];
    int e = 4 * t;
    float vals[4] = {v.x, v.y, v.z, v.w};
#pragma unroll
    for (int j = 0; j < 4; ++j) {
      int p = (e + j) / 3, d = (e + j) % 3;
      if (d == 0) xs[p] = vals[j];
      else if (d == 1) ys[p] = vals[j];
      else zs[p] = vals[j];
    }
  }
  __syncthreads();

  int i = tile * 256 + tid;
  float xi0 = xs[i], xi1 = ys[i], xi2 = zs[i];

  unsigned l[KK];
#pragma unroll
  for (int j = 0; j < KK; ++j) l[j] = 0xFFFFFFFFu;

  int q0 = s * CH;
  // prologue prefetch (wave-uniform LDS float4 reads -> broadcast)
  float4 qx = *(const float4*)&xs[q0];
  float4 qy = *(const float4*)&ys[q0];
  float4 qz = *(const float4*)&zs[q0];
  for (int c = 0; c < CH; c += 4) {
    int qm = (q0 + c + 4) & 1023;  // masked: last prefetch unused
    float4 nqx = *(const float4*)&xs[qm];
    float4 nqy = *(const float4*)&ys[qm];
    float4 nqz = *(const float4*)&zs[qm];
    float cx[4] = {qx.x, qx.y, qx.z, qx.w};
    float cy[4] = {qy.x, qy.y, qy.z, qy.w};
    float cz[4] = {qz.x, qz.y, qz.z, qz.w};
#pragma unroll
    for (int j = 0; j < 4; ++j) {
      float d0 = xi0 - cx[j], d1 = xi1 - cy[j], d2 = xi2 - cz[j];
      float dist = fmaf(d0, d0, fmaf(d1, d1, d2 * d2));
      topk_insert(l, pack_key(dist, q0 + c + j));
    }
    qx = nqx; qy = nqy; qz = nqz;
  }
  size_t base = ((size_t)b * PP + i) * S + s;
#pragma unroll
  for (int j = 0; j < KK; ++j) pk[base * KK + j] = l[j];
}

template <int S>
__global__ __launch_bounds__(256) void knn_merge(const unsigned* __restrict__ pk,
                                                 int* __restrict__ idx_out) {
  int p = blockIdx.x * 256 + threadIdx.x;
  const unsigned* g = pk + (size_t)p * S * KK;
  unsigned l[KK];
#pragma unroll
  for (int j = 0; j < KK; ++j) l[j] = g[j];
  for (int s = 1; s < S; ++s) {
    const unsigned* gs = g + s * KK;
#pragma unroll
    for (int j = 0; j < KK; ++j) topk_insert(l, gs[j]);
  }
#pragma unroll
  for (int j = 0; j < KK; ++j) idx_out[(size_t)p * KK + j] = (int)(l[j] & 1023u);
}

// ---------------- EdgeConv1 precompute ----------------
__global__ __launch_bounds__(256) void precompute1(const float* __restrict__ pos,
                                                   const float* __restrict__ W1,
                                                   const float* __restrict__ b1,
                                                   float* __restrict__ u1,
                                                   float* __restrict__ v1) {
  int gid = blockIdx.x * 256 + threadIdx.x;  // over N*64
  int i = gid >> 6, c = gid & 63;
  float p0 = pos[(size_t)i * 3 + 0], p1 = pos[(size_t)i * 3 + 1], p2 = pos[(size_t)i * 3 + 2];
  float a0 = W1[0 * 64 + c], a1 = W1[1 * 64 + c], a2 = W1[2 * 64 + c];
  float g0 = W1[3 * 64 + c], g1 = W1[4 * 64 + c], g2 = W1[5 * 64 + c];
  float v = fmaf(p0, g0, fmaf(p1, g1, p2 * g2));
  float u = b1[c];
  u = fmaf(p0, a0 - g0, u);
  u = fmaf(p1, a1 - g1, u);
  u = fmaf(p2, a2 - g2, u);
  u1[gid] = u;
  v1[gid] = v;
}

// ---------------- EdgeConv1 via MFMA ----------------
__global__ __launch_bounds__(256) void edge_conv1_mfma(
    const float* __restrict__ u1, const float* __restrict__ v1,
    const int* __restrict__ idx, const float* __restrict__ W2,
    const float* __restrict__ scale, const float* __restrict__ bias,
    const float* __restrict__ b2,
    short* __restrict__ x1h, short* __restrict__ x1l,
    float* __restrict__ sqn) {
  __shared__ float Cs[160 * 68];
  __shared__ int jt[160];
  __shared__ float xs[512];
  int tid = threadIdx.x;
  int p0 = blockIdx.x * 8;
  int b = p0 >> 10;
  if (tid < 160) {
    int e = tid;
    int i = p0 + e / 20;
    jt[e] = (b << 10) + idx[(size_t)i * KK + e % 20];
  }
  int w = tid >> 6, l = tid & 63, quad = l >> 4, lm = l & 15;
  int kq = quad * 8;
  float4 s00 = *(const float4*)(scale + kq);
  float4 s01 = *(const float4*)(scale + kq + 4);
  float4 s10 = *(const float4*)(scale + 32 + kq);
  float4 s11 = *(const float4*)(scale + 32 + kq + 4);
  float4 c00 = *(const float4*)(bias + kq);
  float4 c01 = *(const float4*)(bias + kq + 4);
  float4 c10 = *(const float4*)(bias + 32 + kq);
  float4 c11 = *(const float4*)(bias + 32 + kq + 4);
  bf16x8 Bh[4][2], Bl[4][2];
#pragma unroll
  for (int nt = 0; nt < 4; ++nt) {
#pragma unroll
    for (int ks = 0; ks < 2; ++ks) {
#pragma unroll
      for (int jj = 0; jj < 8; ++jj) {
        float wv = W2[(size_t)(ks * 32 + kq + jj) * 64 + nt * 16 + lm];
        short hi, lo;
        split_bf16(wv, hi, lo);
        Bh[nt][ks][jj] = hi;
        Bl[nt][ks][jj] = lo;
      }
    }
  }
  __syncthreads();

  for (int s = w; s < 10; s += 4) {
    f32x4 acc[4];
#pragma unroll
    for (int nt = 0; nt < 4; ++nt) acc[nt] = (f32x4){0.f, 0.f, 0.f, 0.f};
    int e = s * 16 + lm;
    int p = e / 20;
    int jrow = jt[e];
    const float* urow = u1 + (size_t)(p0 + p) * 64;
    const float* vrow = v1 + (size_t)jrow * 64;
#pragma unroll
    for (int ks = 0; ks < 2; ++ks) {
      int koff = ks * 32 + kq;
      float4 va = *(const float4*)(vrow + koff);
      float4 vb = *(const float4*)(vrow + koff + 4);
      float4 ua = *(const float4*)(urow + koff);
      float4 ub = *(const float4*)(urow + koff + 4);
      float4 sA = ks ? s10 : s00, sB = ks ? s11 : s01;
      float4 cA = ks ? c10 : c00, cB = ks ? c11 : c01;
      float hv[8];
      hv[0] = fmaxf(fmaf(ua.x + va.x, sA.x, cA.x), 0.f);
      hv[1] = fmaxf(fmaf(ua.y + va.y, sA.y, cA.y), 0.f);
      hv[2] = fmaxf(fmaf(ua.z + va.z, sA.z, cA.z), 0.f);
      hv[3] = fmaxf(fmaf(ua.w + va.w, sA.w, cA.w), 0.f);
      hv[4] = fmaxf(fmaf(ub.x + vb.x, sB.x, cB.x), 0.f);
      hv[5] = fmaxf(fmaf(ub.y + vb.y, sB.y, cB.y), 0.f);
      hv[6] = fmaxf(fmaf(ub.z + vb.z, sB.z, cB.z), 0.f);
      hv[7] = fmaxf(fmaf(ub.w + vb.w, sB.w, cB.w), 0.f);
      bf16x8 Ah, Al;
#pragma unroll
      for (int jj = 0; jj < 8; ++jj) {
        short hi, lo;
        split_bf16(hv[jj], hi, lo);
        Ah[jj] = hi;
        Al[jj] = lo;
      }
#pragma unroll
      for (int nt = 0; nt < 4; ++nt) {
        acc[nt] = __builtin_amdgcn_mfma_f32_16x16x32_bf16(Ah, Bh[nt][ks], acc[nt], 0, 0, 0);
        acc[nt] = __builtin_amdgcn_mfma_f32_16x16x32_bf16(Al, Bh[nt][ks], acc[nt], 0, 0, 0);
        acc[nt] = __builtin_amdgcn_mfma_f32_16x16x32_bf16(Ah, Bl[nt][ks], acc[nt], 0, 0, 0);
      }
    }
#pragma unroll
    for (int nt = 0; nt < 4; ++nt) {
#pragma unroll
      for (int r = 0; r < 4; ++r) {
        Cs[(size_t)(s * 16 + quad * 4 + r) * 68 + nt * 16 + lm] = acc[nt][r];
      }
    }
  }
  __syncthreads();
  for (int o = tid; o < 512; o += 256) {
    int p = o >> 6, c = o & 63;
    float m = -__builtin_inff();
    for (int k = 0; k < KK; ++k) m = fmaxf(m, Cs[(size_t)(p * 20 + k) * 68 + c]);
    m += b2[c];
    size_t gi = (size_t)(p0 + p) * 64 + c;
    short hi, lo;
    split_bf16(m, hi, lo);
    x1h[gi] = hi;
    x1l[gi] = lo;
    xs[o] = m;
  }
  __syncthreads();
  if (tid < 8) {
    float ss = 0.f;
    for (int c = 0; c < 64; ++c) {
      float v = xs[tid * 64 + c];
      ss = fmaf(v, v, ss);
    }
    sqn[p0 + tid] = ss;
  }
}

// ---------------- kNN2 via MFMA (S=2, software-pipelined) ----------------
__global__ __launch_bounds__(256) void knn2_mfma(const short* __restrict__ x1h,
                                                 const short* __restrict__ x1l,
                                                 const float* __restrict__ sqn,
                                                 unsigned* __restrict__ pk) {
  __shared__ float sqs[1024];
  int bx = blockIdx.x;
  int s = bx & 1;
  int pb = bx >> 1;
  int p0 = pb * 64;
  int b = p0 >> 10;
  int tid = threadIdx.x;
  for (int t = tid; t < 1024; t += 256) sqs[t] = sqn[(size_t)b * PP + t];
  int w = tid >> 6, l = tid & 63, quad = l >> 4, lm = l & 15;
  size_t gi = (size_t)p0 + w * 16 + lm;
  bf16x8 Bh[2], Bl[2];
#pragma unroll
  for (int ks = 0; ks < 2; ++ks) {
    Bh[ks] = *(const bf16x8*)(x1h + gi * 64 + ks * 32 + quad * 8);
    Bl[ks] = *(const bf16x8*)(x1l + gi * 64 + ks * 32 + quad * 8);
  }
  float sqi = sqn[gi];
  __syncthreads();
  unsigned list[KK];
#pragma unroll
  for (int j = 0; j < KK; ++j) list[j] = 0xFFFFFFFFu;

  const size_t cbase = (size_t)b * PP;
  int m0 = s * 512;
  // prologue prefetch
  bf16x8 Ah[2], Al[2];
  {
    size_t ga = cbase + m0 + lm;
    Ah[0] = *(const bf16x8*)(x1h + ga * 64 + quad * 8);
    Al[0] = *(const bf16x8*)(x1l + ga * 64 + quad * 8);
    Ah[1] = *(const bf16x8*)(x1h + ga * 64 + 32 + quad * 8);
    Al[1] = *(const bf16x8*)(x1l + ga * 64 + 32 + quad * 8);
  }
  float sq0 = sqs[m0 + quad * 4 + 0];
  float sq1 = sqs[m0 + quad * 4 + 1];
  float sq2 = sqs[m0 + quad * 4 + 2];
  float sq3 = sqs[m0 + quad * 4 + 3];

  for (int it = 0; it < 32; ++it) {
    // prefetch next iteration (masked index: last prefetch harmless+unused)
    int m0n = (m0 + 16) & 1023;
    size_t gan = cbase + m0n + lm;
    bf16x8 Ahn0 = *(const bf16x8*)(x1h + gan * 64 + quad * 8);
    bf16x8 Aln0 = *(const bf16x8*)(x1l + gan * 64 + quad * 8);
    bf16x8 Ahn1 = *(const bf16x8*)(x1h + gan * 64 + 32 + quad * 8);
    bf16x8 Aln1 = *(const bf16x8*)(x1l + gan * 64 + 32 + quad * 8);
    float sqn0 = sqs[m0n + quad * 4 + 0];
    float sqn1 = sqs[m0n + quad * 4 + 1];
    float sqn2 = sqs[m0n + quad * 4 + 2];
    float sqn3 = sqs[m0n + quad * 4 + 3];

    // compute on current fragments (same MFMA order as before — bit-exact)
    f32x4 acc = (f32x4){0.f, 0.f, 0.f, 0.f};
    acc = __builtin_amdgcn_mfma_f32_16x16x32_bf16(Ah[0], Bh[0], acc, 0, 0, 0);
    acc = __builtin_amdgcn_mfma_f32_16x16x32_bf16(Al[0], Bh[0], acc, 0, 0, 0);
    acc = __builtin_amdgcn_mfma_f32_16x16x32_bf16(Ah[0], Bl[0], acc, 0, 0, 0);
    acc = __builtin_amdgcn_mfma_f32_16x16x32_bf16(Ah[1], Bh[1], acc, 0, 0, 0);
    acc = __builtin_amdgcn_mfma_f32_16x16x32_bf16(Al[1], Bh[1], acc, 0, 0, 0);
    acc = __builtin_amdgcn_mfma_f32_16x16x32_bf16(Ah[1], Bl[1], acc, 0, 0, 0);

    int qb = m0 + quad * 4;
    float d0 = fmaxf(0.f, fmaf(-2.f, acc[0], sqi + sq0));
    topk_insert(list, pack_key(d0, qb + 0));
    float d1 = fmaxf(0.f, fmaf(-2.f, acc[1], sqi + sq1));
    topk_insert(list, pack_key(d1, qb + 1));
    float d2 = fmaxf(0.f, fmaf(-2.f, acc[2], sqi + sq2));
    topk_insert(list, pack_key(d2, qb + 2));
    float d3 = fmaxf(0.f, fmaf(-2.f, acc[3], sqi + sq3));
    topk_insert(list, pack_key(d3, qb + 3));

    Ah[0] = Ahn0; Al[0] = Aln0; Ah[1] = Ahn1; Al[1] = Aln1;
    sq0 = sqn0; sq1 = sqn1; sq2 = sqn2; sq3 = sqn3;
    m0 += 16;
  }
  unsigned sub = s * 4 + quad;
  unsigned* dst = pk + ((size_t)gi * 8 + sub) * KK;
#pragma unroll
  for (int j = 0; j < KK; ++j) dst[j] = list[j];
}

// ---------------- EdgeConv2 precompute via MFMA ----------------
__global__ __launch_bounds__(256) void pre2_mfma(const short* __restrict__ x1h,
                                                 const short* __restrict__ x1l,
                                                 const float* __restrict__ cW,
                                                 const float* __restrict__ cb,
                                                 float* __restrict__ u2,
                                                 float* __restrict__ v2) {
  constexpr int BS = 72;
  __shared__ short Bh[128 * BS];
  __shared__ short Bl[128 * BS];
  int tid = threadIdx.x;
  int nh = blockIdx.x & 1;
  int p0 = (blockIdx.x >> 1) * 64;
  for (int t = tid; t < 64 * 128; t += 256) {
    int k = t >> 7, n = t & 127;
    float wb_ = cW[(size_t)(64 + k) * 128 + n];
    float wv = nh ? wb_ : (cW[(size_t)k * 128 + n] - wb_);
    short hi, lo;
    split_bf16(wv, hi, lo);
    Bh[n * BS + k] = hi;
    Bl[n * BS + k] = lo;
  }
  __syncthreads();
  int w = tid >> 6, l = tid & 63, quad = l >> 4, lm = l & 15;
  int row = p0 + w * 16 + lm;
  f32x4 acc[8];
#pragma unroll
  for (int nt = 0; nt < 8; ++nt) acc[nt] = (f32x4){0.f, 0.f, 0.f, 0.f};
#pragma unroll
  for (int ks = 0; ks < 2; ++ks) {
    int kb = ks * 32 + quad * 8;
    bf16x8 Ah = *(const bf16x8*)(x1h + (size_t)row * 64 + kb);
    bf16x8 Al = *(const bf16x8*)(x1l + (size_t)row * 64 + kb);
#pragma unroll
    for (int nt = 0; nt < 8; ++nt) {
      bf16x8 Wh = *(const bf16x8*)(Bh + (nt * 16 + lm) * BS + kb);
      bf16x8 Wl = *(const bf16x8*)(Bl + (nt * 16 + lm) * BS + kb);
      acc[nt] = __builtin_amdgcn_mfma_f32_16x16x32_bf16(Ah, Wh, acc[nt], 0, 0, 0);
      acc[nt] = __builtin_amdgcn_mfma_f32_16x16x32_bf16(Al, Wh, acc[nt], 0, 0, 0);
      acc[nt] = __builtin_amdgcn_mfma_f32_16x16x32_bf16(Ah, Wl, acc[nt], 0, 0, 0);
    }
  }
  float* out = nh ? v2 : u2;
  int prow = p0 + w * 16 + quad * 4;
#pragma unroll
  for (int nt = 0; nt < 8; ++nt) {
    int col = nt * 16 + lm;
    float bias = nh ? 0.f : cb[col];
#pragma unroll
    for (int r = 0; r < 4; ++r)
      out[(size_t)(prow + r) * 128 + col] = acc[nt][r] + bias;
  }
}

__global__ __launch_bounds__(256) void gathermax2(const float* __restrict__ u2,
                                                  const float* __restrict__ v2,
                                                  const int* __restrict__ idx,
                                                  short* __restrict__ x2h,
                                                  short* __restrict__ x2l) {
  int gid = blockIdx.x * 256 + threadIdx.x;  // over N*128
  int i = gid >> 7, c = gid & 127;
  int b = i >> 10;
  const int* myidx = idx + (size_t)i * KK;
  float m = -__builtin_inff();
  for (int k = 0; k < KK; ++k) {
    int j = (b << 10) + myidx[k];
    m = fmaxf(m, v2[(size_t)j * 128 + c]);
  }
  float x = u2[gid] + m;
  short hi, lo;
  split_bf16(x, hi, lo);
  x2h[gid] = hi;
  x2l[gid] = lo;
}

// ---------------- final linear via MFMA ----------------
__global__ __launch_bounds__(256) void lin_mfma(const short* __restrict__ x1h,
                                                const short* __restrict__ x1l,
                                                const short* __restrict__ x2h,
                                                const short* __restrict__ x2l,
                                                const float* __restrict__ LW,
                                                const float* __restrict__ lb,
                                                float* __restrict__ h) {
  constexpr int BS = 200;
  __shared__ short Bh[64 * BS];
  __shared__ short Bl[64 * BS];
  int tid = threadIdx.x;
  int nh = blockIdx.x & 1;
  int p0 = (blockIdx.x >> 1) * 64;
  for (int t = tid; t < 192 * 64; t += 256) {
    int k = t >> 6, n = t & 63;
    float wv = LW[(size_t)k * 128 + nh * 64 + n];
    short hi, lo;
    split_bf16(wv, hi, lo);
    Bh[n * BS + k] = hi;
    Bl[n * BS + k] = lo;
  }
  __syncthreads();
  int w = tid >> 6, l = tid & 63, quad = l >> 4, lm = l & 15;
  int row = p0 + w * 16 + lm;
  f32x4 acc[4];
#pragma unroll
  for (int nt = 0; nt < 4; ++nt) acc[nt] = (f32x4){0.f, 0.f, 0.f, 0.f};
#pragma unroll
  for (int ks = 0; ks < 6; ++ks) {
    int kb = ks * 32 + quad * 8;
    bf16x8 Ah, Al;
    if (ks < 2) {
      Ah = *(const bf16x8*)(x1h + (size_t)row * 64 + kb);
      Al = *(const bf16x8*)(x1l + (size_t)row * 64 + kb);
    } else {
      Ah = *(const bf16x8*)(x2h + (size_t)row * 128 + (kb - 64));
      Al = *(const bf16x8*)(x2l + (size_t)row * 128 + (kb - 64));
    }
#pragma unroll
    for (int nt = 0; nt < 4; ++nt) {
      bf16x8 Wh = *(const bf16x8*)(Bh + (nt * 16 + lm) * BS + kb);
      bf16x8 Wl = *(const bf16x8*)(Bl + (nt * 16 + lm) * BS + kb);
      acc[nt] = __builtin_amdgcn_mfma_f32_16x16x32_bf16(Ah, Wh, acc[nt], 0, 0, 0);
      acc[nt] = __builtin_amdgcn_mfma_f32_16x16x32_bf16(Al, Wh, acc[nt], 0, 0, 0);
      acc[nt] = __builtin_amdgcn_mfma_f32_16x16x32_bf16(Ah, Wl, acc[nt], 0, 0, 0);
    }
  }
  int prow = p0 + w * 16 + quad * 4;
#pragma unroll
  for (int nt = 0; nt < 4; ++nt) {
    int col = nh * 64 + nt * 16 + lm;
    float bias = lb[col];
#pragma unroll
    for (int r = 0; r < 4; ++r)
      h[(size_t)(prow + r) * 128 + col] = acc[nt][r] + bias;
  }
}

// ---------------- segment max ----------------
__global__ __launch_bounds__(128) void segmax_a(const float* __restrict__ h,
                                                float* __restrict__ part) {
  int b = blockIdx.x >> 3, chunk = blockIdx.x & 7;
  int c = threadIdx.x;
  float m = -__builtin_inff();
  for (int p = 0; p < 128; ++p) {
    size_t i = (size_t)b * PP + chunk * 128 + p;
    m = fmaxf(m, h[i * 128 + c]);
  }
  part[(size_t)blockIdx.x * 128 + c] = m;
}

__global__ __launch_bounds__(128) void segmax_b(const float* __restrict__ part,
                                                float* __restrict__ out) {
  int b = blockIdx.x;
  int c = threadIdx.x;
  float m = -__builtin_inff();
  for (int k = 0; k < 8; ++k) m = fmaxf(m, part[((size_t)b * 8 + k) * 128 + c]);
  out[(size_t)b * 128 + c] = m;
}

// ---------------- launch ----------------
extern "C" void kernel_launch(void* const* d_in, const int* in_sizes, int n_in,
                              void* d_out, int out_size, void* d_ws, size_t ws_size,
                              hipStream_t stream) {
  const float* pos = (const float*)d_in[0];
  const float* W1 = (const float*)d_in[2];
  const float* b1 = (const float*)d_in[3];
  const float* bn_s = (const float*)d_in[4];
  const float* bn_b = (const float*)d_in[5];
  const float* W2 = (const float*)d_in[6];
  const float* b2 = (const float*)d_in[7];
  const float* cW = (const float*)d_in[8];
  const float* cb = (const float*)d_in[9];
  const float* LW = (const float*)d_in[10];
  const float* lb = (const float*)d_in[11];
  float* out = (float*)d_out;

  char* ws = (char*)d_ws;
  short* x1h = (short*)(ws + OFF_X1);
  short* x1l = (short*)(ws + OFF_X1 + (size_t)NPTS * 64 * 2);
  int* idx = (int*)(ws + OFF_IDX);
  float* u1 = (float*)(ws + OFF_U);
  float* v1 = (float*)(ws + OFF_V);
  float* u2 = (float*)(ws + OFF_U);
  float* v2 = (float*)(ws + OFF_V);
  short* x2h = (short*)(ws + OFF_X2);
  short* x2l = (short*)(ws + OFF_X2 + (size_t)NPTS * 128 * 2);
  float* hbuf = (float*)(ws + OFF_H);
  float* part = (float*)(ws + OFF_PART);
  float* sqn = (float*)(ws + OFF_SQN);
  unsigned* pk = (unsigned*)(ws + OFF_U);  // see lifetime notes above

  // 1. kNN on pos (4-way split)
  knn_topk3<4><<<NB * 4 * 4, 256, 0, stream>>>(pos, pk);
  knn_merge<4><<<NPTS / 256, 256, 0, stream>>>(pk, idx);
  // 2. u1/v1
  precompute1<<<NPTS * 64 / 256, 256, 0, stream>>>(pos, W1, b1, u1, v1);
  // 3. EdgeConv1 (MFMA) -> x1 bf16 hi/lo + sqn
  edge_conv1_mfma<<<NPTS / 8, 256, 0, stream>>>(u1, v1, idx, W2, bn_s, bn_b, b2,
                                                x1h, x1l, sqn);
  // 4. kNN on x1 (MFMA distances, 2-way cand split x 4 quad sublists)
  knn2_mfma<<<NPTS / 64 * 2, 256, 0, stream>>>(x1h, x1l, sqn, pk);
  knn_merge<8><<<NPTS / 256, 256, 0, stream>>>(pk, idx);
  // 5. u2/v2 (MFMA)
  pre2_mfma<<<NPTS / 64 * 2, 256, 0, stream>>>(x1h, x1l, cW, cb, u2, v2);
  // 6. gather + max -> x2 bf16 hi/lo
  gathermax2<<<NPTS * 128 / 256, 256, 0, stream>>>(u2, v2, idx, x2h, x2l);
  // 7. final linear (MFMA) -> h
  lin_mfma<<<NPTS / 64 * 2, 256, 0, stream>>>(x1h, x1l, x2h, x2l, LW, lb, hbuf);
  // 8. segment max -> out
  segmax_a<<<NB * 8, 128, 0, stream>>>(hbuf, part);
  segmax_b<<<NB, 128, 0, stream>>>(part, out);
}